// Round 1
// baseline (178.171 us; speedup 1.0000x reference)
//
#include <hip/hip_runtime.h>
#include <hip/hip_bf16.h>

#define NP  128   // planets per batch
#define NH  64    // hidden dim
#define LDH 72    // LDS row stride in bf16 elems (16B-aligned rows, breaks pow2 banks)

typedef __attribute__((ext_vector_type(8))) short bf16x8;   // 8 bf16 = 4 VGPRs
typedef __attribute__((ext_vector_type(4))) float f32x4;

__device__ __forceinline__ unsigned short bf_bits(float f) {
    __hip_bfloat16 h = __float2bfloat16(f);   // RNE on ROCm7
    return __builtin_bit_cast(unsigned short, h);
}

__global__ void __launch_bounds__(256) gnn_fused(
    const float* __restrict__ planet_xy,  // [B][P][2]
    const float* __restrict__ planet_m,   // [P]
    const float* __restrict__ ast_xy,     // [B][2]
    const float* __restrict__ W1,         // [4][H]
    const float* __restrict__ b1,         // [H]
    const float* __restrict__ W2,         // [H][H]
    const float* __restrict__ b2,         // [H]
    float* __restrict__ out)              // [B][H]
{
    __shared__ alignas(16) float4 sW1T[NH];              // [h] = (W1[0][h],W1[1][h],W1[2][h],W1[3][h])
    __shared__ float sb1[NH];
    __shared__ float sb2[NH];
    __shared__ alignas(16) unsigned short sW2T[NH * LDH]; // [n][k] = bf16(W2[k][n])
    __shared__ alignas(16) unsigned short sH[NP * LDH];   // [p][k] = bf16(h[p][k])
    __shared__ float sPart[4][NH];

    const int tid = threadIdx.x;
    const int b   = blockIdx.x;

    // ---- per-thread feats (global loads issued before barrier) ----
    const int p     = tid & 127;        // two threads per planet
    const int jbase = (tid >> 7) * 32;  // wave-uniform half of H
    float2 pxy = ((const float2*)planet_xy)[(size_t)b * NP + p];
    float ax = ast_xy[2 * b];
    float ay = ast_xy[2 * b + 1];
    float pm = planet_m[p];

    // ---- stage W1T / b1 / b2 ----
    if (tid < NH) {
        sW1T[tid] = make_float4(W1[tid], W1[NH + tid], W1[2 * NH + tid], W1[3 * NH + tid]);
        sb1[tid] = b1[tid];
        sb2[tid] = b2[tid];
    }
    // ---- stage W2 -> LDS, transposed, bf16 ----
    {
        const int n  = tid & 63;
        const int kb = (tid >> 6) * 16;
        #pragma unroll
        for (int i = 0; i < 16; i += 4) {
            const int k = kb + i;
            float a0 = W2[(k + 0) * NH + n];   // coalesced across lanes (n contiguous)
            float a1 = W2[(k + 1) * NH + n];
            float a2 = W2[(k + 2) * NH + n];
            float a3 = W2[(k + 3) * NH + n];
            ushort4 pk;
            pk.x = bf_bits(a0); pk.y = bf_bits(a1);
            pk.z = bf_bits(a2); pk.w = bf_bits(a3);
            *(ushort4*)&sW2T[n * LDH + k] = pk;  // 8B store, aligned
        }
    }

    float dx = pxy.x - ax;
    float dy = pxy.y - ay;
    float dist2 = fmaf(dx, dx, fmaf(dy, dy, 1e-6f));
    float inv = 1.0f / sqrtf(dist2);

    __syncthreads();

    // ---- layer 1: h = relu(feats @ W1 + b1), fp32 VALU, write bf16 to LDS ----
    #pragma unroll
    for (int jj = 0; jj < 32; jj += 4) {
        const int j = jbase + jj;
        float4 w0 = sW1T[j + 0];
        float4 w1v = sW1T[j + 1];
        float4 w2v = sW1T[j + 2];
        float4 w3v = sW1T[j + 3];
        float v0 = fmaf(pm, w0.w,  fmaf(inv, w0.z,  fmaf(dy, w0.y,  fmaf(dx, w0.x,  sb1[j + 0]))));
        float v1 = fmaf(pm, w1v.w, fmaf(inv, w1v.z, fmaf(dy, w1v.y, fmaf(dx, w1v.x, sb1[j + 1]))));
        float v2 = fmaf(pm, w2v.w, fmaf(inv, w2v.z, fmaf(dy, w2v.y, fmaf(dx, w2v.x, sb1[j + 2]))));
        float v3 = fmaf(pm, w3v.w, fmaf(inv, w3v.z, fmaf(dy, w3v.y, fmaf(dx, w3v.x, sb1[j + 3]))));
        ushort4 pk;
        pk.x = bf_bits(fmaxf(v0, 0.0f));
        pk.y = bf_bits(fmaxf(v1, 0.0f));
        pk.z = bf_bits(fmaxf(v2, 0.0f));
        pk.w = bf_bits(fmaxf(v3, 0.0f));
        *(ushort4*)&sH[p * LDH + j] = pk;
    }

    __syncthreads();

    // ---- layer 2: msg = relu(h @ W2 + b2) via MFMA, fused column-sum ----
    const int wv   = tid >> 6;
    const int lane = tid & 63;
    const int q    = lane >> 4;
    const int lm   = lane & 15;

    // B fragments: B[k][n], lane holds n = lm, k = 32*kk + 8*q + j (8 contiguous in W2T row)
    bf16x8 bfrag[4][2];
    #pragma unroll
    for (int n = 0; n < 4; n++)
        #pragma unroll
        for (int kk = 0; kk < 2; kk++)
            bfrag[n][kk] = *(const bf16x8*)&sW2T[(n * 16 + lm) * LDH + kk * 32 + q * 8];

    f32x4 acc[2][4];
    #pragma unroll
    for (int mi = 0; mi < 2; mi++)
        #pragma unroll
        for (int n = 0; n < 4; n++)
            acc[mi][n] = (f32x4){0.f, 0.f, 0.f, 0.f};

    #pragma unroll
    for (int mi = 0; mi < 2; mi++) {
        const int row = wv * 32 + mi * 16 + lm;   // A[m=lm][k=q*8+j]
        #pragma unroll
        for (int kk = 0; kk < 2; kk++) {
            bf16x8 afrag = *(const bf16x8*)&sH[row * LDH + kk * 32 + q * 8];
            #pragma unroll
            for (int n = 0; n < 4; n++)
                acc[mi][n] = __builtin_amdgcn_mfma_f32_16x16x32_bf16(
                    afrag, bfrag[n][kk], acc[mi][n], 0, 0, 0);
        }
    }

    // ---- epilogue: relu(acc + b2), sum over rows (C/D: col=lm, row=q*4+r) ----
    #pragma unroll
    for (int n = 0; n < 4; n++) {
        const float bias = sb2[n * 16 + lm];
        float s = 0.0f;
        #pragma unroll
        for (int mi = 0; mi < 2; mi++)
            #pragma unroll
            for (int r = 0; r < 4; r++)
                s += fmaxf(acc[mi][n][r] + bias, 0.0f);
        s += __shfl_xor(s, 16, 64);   // reduce across quads (rows)
        s += __shfl_xor(s, 32, 64);
        if (q == 0) sPart[wv][n * 16 + lm] = s;
    }
    __syncthreads();
    if (tid < NH) {
        out[(size_t)b * NH + tid] = sPart[0][tid] + sPart[1][tid] + sPart[2][tid] + sPart[3][tid];
    }
}

extern "C" void kernel_launch(void* const* d_in, const int* in_sizes, int n_in,
                              void* d_out, int out_size, void* d_ws, size_t ws_size,
                              hipStream_t stream) {
    const float* planet_xy = (const float*)d_in[0];
    const float* planet_m  = (const float*)d_in[1];
    const float* ast_xy    = (const float*)d_in[2];
    const float* W1        = (const float*)d_in[3];
    const float* b1        = (const float*)d_in[4];
    const float* W2        = (const float*)d_in[5];
    const float* b2        = (const float*)d_in[6];
    float* outp            = (float*)d_out;

    const int B = in_sizes[2] / 2;   // ast_xy is [B][2]
    gnn_fused<<<B, 256, 0, stream>>>(planet_xy, planet_m, ast_xy, W1, b1, W2, b2, outp);
}

// Round 3
// 171.231 us; speedup vs baseline: 1.0405x; 1.0405x over previous
//
#include <hip/hip_runtime.h>
#include <hip/hip_fp16.h>

#define NP   128   // planets per batch
#define NH   64    // hidden dim
#define LDH  72    // sH row stride in f16 elems (conflict-free for b64 writes + b128 reads)

typedef __attribute__((ext_vector_type(8))) _Float16 f16x8;   // 4 VGPRs, MFMA A/B operand
typedef __attribute__((ext_vector_type(2))) __fp16  hf16x2;   // return type of cvt_pkrtz
typedef __attribute__((ext_vector_type(4))) float f32x4;

union F16Frag {
    f16x8 v;
    unsigned int u[4];
    uint4 u4;
};

__device__ __forceinline__ unsigned int pack_pkrtz(float a, float b) {
    hf16x2 t = __builtin_amdgcn_cvt_pkrtz(a, b);
    return __builtin_bit_cast(unsigned int, t);
}

// ---------------------------------------------------------------------------
// Pre-kernel: build per-lane f16 MFMA fragments of W1 / W2 in workspace.
//   ws[0      .. 2047]  : w1a frags  [mt(4)][lane(64)][j(8)]   A-layout, K padded 4->32
//   ws[2048   .. 6143]  : w2  frags  [kk(2)][np(4)][lane(64)][j(8)]  B-layout
// ---------------------------------------------------------------------------
__global__ void prep_weights(const float* __restrict__ W1,   // [4][64]
                             const float* __restrict__ W2,   // [64][64]
                             unsigned short* __restrict__ ws)
{
    const int t = threadIdx.x;  // 256 threads
    // --- W1 A-fragments (transposed layer1: A[m=h-idx][k=feat]) ---
    {
        const int mt = t >> 6, lane = t & 63;
        const int q = lane >> 4, lm = lane & 15;
        union { unsigned short v[8]; uint4 u; } pk;
        #pragma unroll
        for (int j = 0; j < 8; j++) {
            float x = (q == 0 && j < 4) ? W1[j * NH + 16 * mt + lm] : 0.0f;
            pk.v[j] = __builtin_bit_cast(unsigned short, __float2half(x));
        }
        *(uint4*)&ws[(mt * 64 + lane) * 8] = pk.u;
    }
    // --- W2 B-fragments: B[k=32kk+8q+j][n=16np+lm] = W2[k][n] ---
    #pragma unroll
    for (int it = 0; it < 2; ++it) {
        const int e = it * 256 + t;            // 0..511
        const int lane = e & 63, fi = e >> 6;  // fi = kk*4+np
        const int kk = fi >> 2, np = fi & 3;
        const int q = lane >> 4, lm = lane & 15;
        union { unsigned short v[8]; uint4 u; } pk;
        #pragma unroll
        for (int j = 0; j < 8; j++) {
            float x = W2[(32 * kk + 8 * q + j) * NH + 16 * np + lm];
            pk.v[j] = __builtin_bit_cast(unsigned short, __float2half(x));
        }
        *(uint4*)&ws[2048 + e * 8] = pk.u;
    }
}

// ---------------------------------------------------------------------------
// Main kernel: one block per batch, 4 waves. Both layers on MFMA (f16).
// ---------------------------------------------------------------------------
__global__ void __launch_bounds__(256) gnn_fused(
    const float* __restrict__ planet_xy,  // [B][P][2]
    const float* __restrict__ planet_m,   // [P]
    const float* __restrict__ ast_xy,     // [B][2]
    const float* __restrict__ b1,         // [H]
    const float* __restrict__ b2,         // [H]
    const unsigned short* __restrict__ ws,
    float* __restrict__ out)              // [B][H]
{
    __shared__ alignas(16) unsigned short sH[NP * LDH];  // h[p][k] in f16 bits
    __shared__ float sPart[4][NH];

    const int tid  = threadIdx.x;
    const int b    = blockIdx.x;
    const int wv   = tid >> 6;
    const int lane = tid & 63;
    const int q    = lane >> 4;
    const int lm   = lane & 15;

    // ---- prefetch weight fragments into registers (L1/L2-resident) ----
    F16Frag w1f[4];
    #pragma unroll
    for (int mt = 0; mt < 4; mt++)
        w1f[mt].u4 = *(const uint4*)&ws[(mt * 64 + lane) * 8];

    F16Frag w2f[2][4];
    #pragma unroll
    for (int kk = 0; kk < 2; kk++)
        #pragma unroll
        for (int np = 0; np < 4; np++)
            w2f[kk][np].u4 = *(const uint4*)&ws[2048 + ((kk * 4 + np) * 64 + lane) * 8];

    // ---- bias fragments (acc init): b1 rows 16mt+4q..+3 ; b2 col 16np+lm ----
    f32x4 b1f[4];
    #pragma unroll
    for (int mt = 0; mt < 4; mt++)
        b1f[mt] = *(const f32x4*)&b1[16 * mt + 4 * q];

    float b2v[4];
    #pragma unroll
    for (int np = 0; np < 4; np++)
        b2v[np] = b2[16 * np + lm];

    // ---- feats for this wave's 2 planet-columns (B-fragments of layer1) ----
    const float2 axy = *(const float2*)&ast_xy[2 * b];
    F16Frag bfeat[2];
    #pragma unroll
    for (int nti = 0; nti < 2; nti++) {
        const int p = 32 * wv + nti * 16 + lm;
        float2 pxy = *(const float2*)&planet_xy[((size_t)b * NP + p) * 2];
        float pm = planet_m[p];
        float dx = pxy.x - axy.x;
        float dy = pxy.y - axy.y;
        float inv = __builtin_amdgcn_rsqf(fmaf(dx, dx, fmaf(dy, dy, 1e-6f)));
        unsigned int lo = pack_pkrtz(dx, dy);
        unsigned int hi = pack_pkrtz(inv, pm);
        bfeat[nti].u[0] = (q == 0) ? lo : 0u;
        bfeat[nti].u[1] = (q == 0) ? hi : 0u;
        bfeat[nti].u[2] = 0u;
        bfeat[nti].u[3] = 0u;
    }

    // ---- layer 1 (transposed): hT = W1T @ featsT + b1, relu, -> sH ----
    // C/D layout: row = h-idx 16mt+4q+r, col = planet 32wv+16nti+lm
    #pragma unroll
    for (int nti = 0; nti < 2; nti++) {
        const int p = 32 * wv + nti * 16 + lm;
        #pragma unroll
        for (int mt = 0; mt < 4; mt++) {
            f32x4 acc = b1f[mt];
            acc = __builtin_amdgcn_mfma_f32_16x16x32_f16(w1f[mt].v, bfeat[nti].v, acc, 0, 0, 0);
            unsigned int d0 = pack_pkrtz(fmaxf(acc[0], 0.0f), fmaxf(acc[1], 0.0f));
            unsigned int d1 = pack_pkrtz(fmaxf(acc[2], 0.0f), fmaxf(acc[3], 0.0f));
            uint2 d = make_uint2(d0, d1);
            *(uint2*)&sH[p * LDH + 16 * mt + 4 * q] = d;   // ds_write_b64, conflict-free
        }
    }

    __syncthreads();

    // ---- layer 2: msg = relu(h @ W2 + b2), fused column-sum ----
    f32x4 acc2[2][4];
    #pragma unroll
    for (int mi = 0; mi < 2; mi++)
        #pragma unroll
        for (int np = 0; np < 4; np++)
            acc2[mi][np] = (f32x4){b2v[np], b2v[np], b2v[np], b2v[np]};

    #pragma unroll
    for (int kk = 0; kk < 2; kk++)
        #pragma unroll
        for (int mi = 0; mi < 2; mi++) {
            const int row = 32 * wv + 16 * mi + lm;          // planet row (A: m=lm)
            f16x8 a = *(const f16x8*)&sH[row * LDH + 32 * kk + 8 * q];  // ds_read_b128
            #pragma unroll
            for (int np = 0; np < 4; np++)
                acc2[mi][np] = __builtin_amdgcn_mfma_f32_16x16x32_f16(
                    a, w2f[kk][np].v, acc2[mi][np], 0, 0, 0);
        }

    // ---- epilogue: relu + sum over planet rows ----
    #pragma unroll
    for (int np = 0; np < 4; np++) {
        float s = 0.0f;
        #pragma unroll
        for (int mi = 0; mi < 2; mi++)
            #pragma unroll
            for (int r = 0; r < 4; r++)
                s += fmaxf(acc2[mi][np][r], 0.0f);
        s += __shfl_xor(s, 16, 64);
        s += __shfl_xor(s, 32, 64);
        if (q == 0) sPart[wv][16 * np + lm] = s;
    }
    __syncthreads();

    if (tid < NH)
        out[(size_t)b * NH + tid] = sPart[0][tid] + sPart[1][tid] + sPart[2][tid] + sPart[3][tid];
}

extern "C" void kernel_launch(void* const* d_in, const int* in_sizes, int n_in,
                              void* d_out, int out_size, void* d_ws, size_t ws_size,
                              hipStream_t stream) {
    const float* planet_xy = (const float*)d_in[0];
    const float* planet_m  = (const float*)d_in[1];
    const float* ast_xy    = (const float*)d_in[2];
    const float* W1        = (const float*)d_in[3];
    const float* b1        = (const float*)d_in[4];
    const float* W2        = (const float*)d_in[5];
    const float* b2        = (const float*)d_in[6];
    float* outp            = (float*)d_out;
    unsigned short* ws     = (unsigned short*)d_ws;

    const int B = in_sizes[2] / 2;   // ast_xy is [B][2]

    prep_weights<<<1, 256, 0, stream>>>(W1, W2, ws);
    gnn_fused<<<B, 256, 0, stream>>>(planet_xy, planet_m, ast_xy, b1, b2, ws, outp);
}

// Round 4
// 161.802 us; speedup vs baseline: 1.1012x; 1.0583x over previous
//
#include <hip/hip_runtime.h>
#include <hip/hip_fp16.h>

#define NP    128   // planets per batch
#define NH    64    // hidden dim
#define LDH   72    // sH row stride in f16 elems (conflict-free for b64 writes + b128 reads)
#define ITERS 8     // batches per block (grid-stride)

typedef __attribute__((ext_vector_type(8))) _Float16 f16x8;   // 4 VGPRs, MFMA A/B operand
typedef __attribute__((ext_vector_type(2))) __fp16  hf16x2;   // return type of cvt_pkrtz
typedef __attribute__((ext_vector_type(4))) float f32x4;

union F16Frag {
    f16x8 v;
    unsigned int u[4];
    uint4 u4;
};

__device__ __forceinline__ unsigned int pack_pkrtz(float a, float b) {
    hf16x2 t = __builtin_amdgcn_cvt_pkrtz(a, b);
    return __builtin_bit_cast(unsigned int, t);
}

// ---------------------------------------------------------------------------
// Pre-kernel: build per-lane f16 MFMA fragments of W1 / W2 in workspace.
//   ws[0      .. 2047]  : w1a frags  [mt(4)][lane(64)][j(8)]   A-layout, K padded 4->32
//   ws[2048   .. 6143]  : w2  frags  [kk(2)][np(4)][lane(64)][j(8)]  B-layout
// ---------------------------------------------------------------------------
__global__ void prep_weights(const float* __restrict__ W1,   // [4][64]
                             const float* __restrict__ W2,   // [64][64]
                             unsigned short* __restrict__ ws)
{
    const int t = threadIdx.x;  // 256 threads
    {
        const int mt = t >> 6, lane = t & 63;
        const int q = lane >> 4, lm = lane & 15;
        union { unsigned short v[8]; uint4 u; } pk;
        #pragma unroll
        for (int j = 0; j < 8; j++) {
            float x = (q == 0 && j < 4) ? W1[j * NH + 16 * mt + lm] : 0.0f;
            pk.v[j] = __builtin_bit_cast(unsigned short, __float2half(x));
        }
        *(uint4*)&ws[(mt * 64 + lane) * 8] = pk.u;
    }
    #pragma unroll
    for (int it = 0; it < 2; ++it) {
        const int e = it * 256 + t;            // 0..511
        const int lane = e & 63, fi = e >> 6;  // fi = kk*4+np
        const int kk = fi >> 2, np = fi & 3;
        const int q = lane >> 4, lm = lane & 15;
        union { unsigned short v[8]; uint4 u; } pk;
        #pragma unroll
        for (int j = 0; j < 8; j++) {
            float x = W2[(32 * kk + 8 * q + j) * NH + 16 * np + lm];
            pk.v[j] = __builtin_bit_cast(unsigned short, __float2half(x));
        }
        *(uint4*)&ws[2048 + e * 8] = pk.u;
    }
}

// ---------------------------------------------------------------------------
// Main kernel: one block handles ITERS consecutive batches. Weight fragments
// loaded once per block; planet/asteroid loads prefetched one iter ahead.
// ---------------------------------------------------------------------------
__global__ void __launch_bounds__(256) gnn_fused(
    const float* __restrict__ planet_xy,  // [B][P][2]
    const float* __restrict__ planet_m,   // [P]
    const float* __restrict__ ast_xy,     // [B][2]
    const float* __restrict__ b1,         // [H]
    const float* __restrict__ b2,         // [H]
    const unsigned short* __restrict__ ws,
    float* __restrict__ out,              // [B][H]
    int B)
{
    __shared__ alignas(16) unsigned short sH[NP * LDH];  // h[p][k] in f16 bits
    __shared__ float sPart[2][4][NH];                    // parity-buffered partials

    const int tid  = threadIdx.x;
    const int wv   = tid >> 6;
    const int lane = tid & 63;
    const int q    = lane >> 4;
    const int lm   = lane & 15;

    // ---- weight fragments: once per block (L1/L2-resident) ----
    F16Frag w1f[4];
    #pragma unroll
    for (int mt = 0; mt < 4; mt++)
        w1f[mt].u4 = *(const uint4*)&ws[(mt * 64 + lane) * 8];

    F16Frag w2f[2][4];
    #pragma unroll
    for (int kk = 0; kk < 2; kk++)
        #pragma unroll
        for (int np = 0; np < 4; np++)
            w2f[kk][np].u4 = *(const uint4*)&ws[2048 + ((kk * 4 + np) * 64 + lane) * 8];

    f32x4 b1f[4];
    #pragma unroll
    for (int mt = 0; mt < 4; mt++)
        b1f[mt] = *(const f32x4*)&b1[16 * mt + 4 * q];

    float b2v[4];
    #pragma unroll
    for (int np = 0; np < 4; np++)
        b2v[np] = b2[16 * np + lm];

    // ---- batch-invariant planet data: once per block ----
    const int p0 = 32 * wv + lm;        // nti = 0
    const int p1 = p0 + 16;             // nti = 1
    const float pm0 = planet_m[p0];
    const float pm1 = planet_m[p1];

    int b = blockIdx.x * ITERS;

    // ---- prefetch iter 0 ----
    float2 pxy0 = *(const float2*)&planet_xy[((size_t)b * NP + p0) * 2];
    float2 pxy1 = *(const float2*)&planet_xy[((size_t)b * NP + p1) * 2];
    float2 axy  = *(const float2*)&ast_xy[2 * b];

    for (int it = 0; it < ITERS; ++it, ++b) {
        // ---- feats for this wave's 2 planet-columns ----
        F16Frag bfeat[2];
        {
            float dx0 = pxy0.x - axy.x, dy0 = pxy0.y - axy.y;
            float dx1 = pxy1.x - axy.x, dy1 = pxy1.y - axy.y;
            float inv0 = __builtin_amdgcn_rsqf(fmaf(dx0, dx0, fmaf(dy0, dy0, 1e-6f)));
            float inv1 = __builtin_amdgcn_rsqf(fmaf(dx1, dx1, fmaf(dy1, dy1, 1e-6f)));
            bfeat[0].u[0] = (q == 0) ? pack_pkrtz(dx0, dy0)  : 0u;
            bfeat[0].u[1] = (q == 0) ? pack_pkrtz(inv0, pm0) : 0u;
            bfeat[0].u[2] = 0u; bfeat[0].u[3] = 0u;
            bfeat[1].u[0] = (q == 0) ? pack_pkrtz(dx1, dy1)  : 0u;
            bfeat[1].u[1] = (q == 0) ? pack_pkrtz(inv1, pm1) : 0u;
            bfeat[1].u[2] = 0u; bfeat[1].u[3] = 0u;
        }

        // ---- prefetch next iteration (overlaps MFMA/LDS below) ----
        {
            const int bn = (it + 1 < ITERS) ? b + 1 : b;
            pxy0 = *(const float2*)&planet_xy[((size_t)bn * NP + p0) * 2];
            pxy1 = *(const float2*)&planet_xy[((size_t)bn * NP + p1) * 2];
            axy  = *(const float2*)&ast_xy[2 * bn];
        }

        // ---- layer 1 (transposed): hT = W1T @ featsT + b1, relu -> sH ----
        #pragma unroll
        for (int nti = 0; nti < 2; nti++) {
            const int p = 32 * wv + 16 * nti + lm;
            #pragma unroll
            for (int mt = 0; mt < 4; mt++) {
                f32x4 acc = b1f[mt];
                acc = __builtin_amdgcn_mfma_f32_16x16x32_f16(w1f[mt].v, bfeat[nti].v, acc, 0, 0, 0);
                unsigned int d0 = pack_pkrtz(fmaxf(acc[0], 0.0f), fmaxf(acc[1], 0.0f));
                unsigned int d1 = pack_pkrtz(fmaxf(acc[2], 0.0f), fmaxf(acc[3], 0.0f));
                *(uint2*)&sH[p * LDH + 16 * mt + 4 * q] = make_uint2(d0, d1);
            }
        }

        __syncthreads();

        // ---- layer 2: msg = relu(h @ W2 + b2), fused column-sum ----
        f32x4 acc2[2][4];
        #pragma unroll
        for (int mi = 0; mi < 2; mi++)
            #pragma unroll
            for (int np = 0; np < 4; np++)
                acc2[mi][np] = (f32x4){b2v[np], b2v[np], b2v[np], b2v[np]};

        #pragma unroll
        for (int kk = 0; kk < 2; kk++)
            #pragma unroll
            for (int mi = 0; mi < 2; mi++) {
                const int row = 32 * wv + 16 * mi + lm;
                f16x8 a = *(const f16x8*)&sH[row * LDH + 32 * kk + 8 * q];
                #pragma unroll
                for (int np = 0; np < 4; np++)
                    acc2[mi][np] = __builtin_amdgcn_mfma_f32_16x16x32_f16(
                        a, w2f[kk][np].v, acc2[mi][np], 0, 0, 0);
            }

        // ---- epilogue: relu + sum over planet rows ----
        const int par = it & 1;
        #pragma unroll
        for (int np = 0; np < 4; np++) {
            float s = 0.0f;
            #pragma unroll
            for (int mi = 0; mi < 2; mi++)
                #pragma unroll
                for (int r = 0; r < 4; r++)
                    s += fmaxf(acc2[mi][np][r], 0.0f);
            s += __shfl_xor(s, 16, 64);
            s += __shfl_xor(s, 32, 64);
            if (q == 0) sPart[par][wv][16 * np + lm] = s;
        }

        __syncthreads();

        if (tid < NH && b < B) {
            out[(size_t)b * NH + tid] = sPart[par][0][tid] + sPart[par][1][tid]
                                      + sPart[par][2][tid] + sPart[par][3][tid];
        }
        // next iter's sH writes are WAR-safe: all waves passed the barrier above,
        // and their sH reads completed before it. sPart parity gives the out-read
        // two barriers of separation from the next write to the same buffer.
    }
}

extern "C" void kernel_launch(void* const* d_in, const int* in_sizes, int n_in,
                              void* d_out, int out_size, void* d_ws, size_t ws_size,
                              hipStream_t stream) {
    const float* planet_xy = (const float*)d_in[0];
    const float* planet_m  = (const float*)d_in[1];
    const float* ast_xy    = (const float*)d_in[2];
    const float* W1        = (const float*)d_in[3];
    const float* b1        = (const float*)d_in[4];
    const float* W2        = (const float*)d_in[5];
    const float* b2        = (const float*)d_in[6];
    float* outp            = (float*)d_out;
    unsigned short* ws     = (unsigned short*)d_ws;

    const int B = in_sizes[2] / 2;   // ast_xy is [B][2]
    const int grid = (B + ITERS - 1) / ITERS;

    prep_weights<<<1, 256, 0, stream>>>(W1, W2, ws);
    gnn_fused<<<grid, 256, 0, stream>>>(planet_xy, planet_m, ast_xy, b1, b2, ws, outp, B);
}